// Round 4
// baseline (249.968 us; speedup 1.0000x reference)
//
#include <hip/hip_runtime.h>

#define NPI    33600     // anchors per image: 160^2 + 80^2 + 40^2
#define KTOP   500
#define CAP    1024
#define KEY001 0xBC23D70Au   // monotonic key of 0.01f
#define NGRP   1024
#define NIMG   8

__device__ __forceinline__ float sigmoidf_(float x) {
  return 1.0f / (1.0f + expf(-x));
}
// monotonic float -> u32 key (order-preserving for all non-NaN floats)
__device__ __forceinline__ unsigned fkey(float f) {
  unsigned u = __float_as_uint(f);
  return (u & 0x80000000u) ? ~u : (u | 0x80000000u);
}

// ---------------- Kernel 1: streaming decode + keys + fused coarse hist ----------
// 4 anchors/thread, float4 (16B/lane) channel reads, 8-deep load batches.
// Level boundaries (25600, 32000) are multiples of 4 -> no 4-group straddles.
__global__ __launch_bounds__(256) void k_decode(
    const float* __restrict__ p8, const float* __restrict__ p16,
    const float* __restrict__ p32,
    unsigned* __restrict__ keys, float* __restrict__ dets,
    unsigned* __restrict__ hist2)
{
  const int b = blockIdx.y;
  const int t = blockIdx.x * 256 + threadIdx.x;
  const int a = t * 4;
  __shared__ unsigned lh[NGRP];
  for (int i = threadIdx.x; i < NGRP; i += 256) lh[i] = 0;
  __syncthreads();

  if (a < NPI) {
    const float* lvl; int j, W, HW, S;
    if (a < 25600)      { lvl = p8;  j = a;         W = 160; HW = 25600; S = 8;  }
    else if (a < 32000) { lvl = p16; j = a - 25600; W = 80;  HW = 6400;  S = 16; }
    else                { lvl = p32; j = a - 32000; W = 40;  HW = 1600;  S = 32; }
    const float* base = lvl + (size_t)b * 85 * HW + j;
    float4 t0 = *(const float4*)(base);
    float4 t1 = *(const float4*)(base + (size_t)1 * HW);
    float4 t2 = *(const float4*)(base + (size_t)2 * HW);
    float4 t3 = *(const float4*)(base + (size_t)3 * HW);
    float4 t4 = *(const float4*)(base + (size_t)4 * HW);
    // exact per-class sigmoid argmax, first occurrence (strict >)
    float cc[4] = {-1.0f, -1.0f, -1.0f, -1.0f};
    int   lab[4] = {0, 0, 0, 0};
    #pragma unroll
    for (int c0 = 0; c0 < 80; c0 += 8) {
      float4 r[8];
      #pragma unroll
      for (int u = 0; u < 8; ++u)
        r[u] = *(const float4*)(base + (size_t)(5 + c0 + u) * HW);
      #pragma unroll
      for (int u = 0; u < 8; ++u) {
        float s;
        s = sigmoidf_(r[u].x); if (s > cc[0]) { cc[0] = s; lab[0] = c0 + u; }
        s = sigmoidf_(r[u].y); if (s > cc[1]) { cc[1] = s; lab[1] = c0 + u; }
        s = sigmoidf_(r[u].z); if (s > cc[2]) { cc[2] = s; lab[2] = c0 + u; }
        s = sigmoidf_(r[u].w); if (s > cc[3]) { cc[3] = s; lab[3] = c0 + u; }
      }
    }
    float e0[4] = {t0.x, t0.y, t0.z, t0.w};
    float e1[4] = {t1.x, t1.y, t1.z, t1.w};
    float e2[4] = {t2.x, t2.y, t2.z, t2.w};
    float e3[4] = {t3.x, t3.y, t3.z, t3.w};
    float e4[4] = {t4.x, t4.y, t4.z, t4.w};
    unsigned k4[4];
    float dv[7][4];
    #pragma unroll
    for (int e = 0; e < 4; ++e) {
      float obj = sigmoidf_(e4[e]);
      float tot = obj * cc[e];          // == sigmoid(obj)*sigmoid(max raw) bitwise
      k4[e] = fkey(tot >= 0.01f ? tot : -1.0f);
      int jj = j + e;
      int gy = jj / W, gx = jj - gy * W;
      float fs = (float)S;
      float cx = (e0[e] + (float)gx) * fs;
      float cy = (e1[e] + (float)gy) * fs;
      float w  = expf(e2[e]) * fs;
      float h  = expf(e3[e]) * fs;
      dv[0][e] = cx - 0.5f * w; dv[1][e] = cy - 0.5f * h;
      dv[2][e] = cx + 0.5f * w; dv[3][e] = cy + 0.5f * h;
      dv[4][e] = obj; dv[5][e] = cc[e]; dv[6][e] = (float)lab[e];
    }
    *(uint4*)(keys + (size_t)b * NPI + a) = make_uint4(k4[0], k4[1], k4[2], k4[3]);
    const size_t P  = (size_t)NIMG * NPI;
    const size_t pa = (size_t)b * NPI + a;
    #pragma unroll
    for (int c = 0; c < 7; ++c)
      *(float4*)(dets + (size_t)c * P + pa) =
          make_float4(dv[c][0], dv[c][1], dv[c][2], dv[c][3]);
    #pragma unroll
    for (int e = 0; e < 4; ++e) atomicAdd(&lh[k4[e] >> 22], 1u);
  }
  __syncthreads();
  unsigned* gb = hist2 + (size_t)b * NGRP;
  for (int i = threadIdx.x; i < NGRP; i += 256) {
    unsigned v = lh[i];
    if (v) atomicAdd(&gb[i], v);
  }
}

// ---------------- Kernel 2: per-image select + sort + gather + IoU + NMS ----------
__global__ __launch_bounds__(1024) void k_post(
    const unsigned* __restrict__ hist2, const unsigned* __restrict__ keys,
    const float* __restrict__ dets, float* __restrict__ out)
{
  const int b    = blockIdx.x;
  const int tid  = threadIdx.x;
  const int lane = tid & 63;
  const int wave = tid >> 6;

  __shared__ unsigned lh[NGRP];          // 4 KB (preloaded hist)
  __shared__ unsigned sh_sub[4096];      // 16 KB refine hist
  __shared__ unsigned sh_c64[64];
  __shared__ unsigned sh_G, sh_Chi10, sh_T, sh_Chi, sh_nA, sh_nB;
  __shared__ unsigned long long sh_cand[CAP];   // 8 KB
  __shared__ float sh_det[KTOP][7];      // 14 KB
  __shared__ float sh_box[KTOP][4];      // 8 KB
  __shared__ unsigned sh_mask[KTOP * 16];// 32 KB
  __shared__ unsigned sh_inval[16];
  __shared__ unsigned sh_keep[16];
  __shared__ unsigned sh_wcA[16], sh_wcB[16];
  __shared__ float sh_red[16];
  __shared__ float sh_maxc;

  // ---- Phase A1: load precomputed coarse hist; find boundary 10-bit group G
  lh[tid] = hist2[(size_t)b * NGRP + tid];
  for (int i = tid; i < 4096; i += 1024) sh_sub[i] = 0;
  __syncthreads();
  if (tid < 64) {
    unsigned s = 0;
    #pragma unroll
    for (int k = 0; k < 16; ++k) s += lh[tid * 16 + k];
    sh_c64[tid] = s;
  }
  __syncthreads();
  if (tid == 0) {
    unsigned cum = 0; int C = 0;
    for (int g = 63; g >= 0; --g) {
      unsigned v = sh_c64[g];
      if (cum + v >= KTOP) { C = g; break; }
      cum += v;
    }
    int G = C * 16; unsigned chi = cum;
    for (int g = C * 16 + 15; g >= C * 16; --g) {
      unsigned v = lh[g];
      if (chi + v >= KTOP) { G = g; break; }
      chi += v;
    }
    sh_G = (unsigned)G; sh_Chi10 = chi;
    sh_nA = 0; sh_nB = 0;
  }
  __syncthreads();
  const unsigned G = sh_G;
  const unsigned* kb = keys + (size_t)b * NPI;

  // ---- Phase A2: 4096-bin sub-hist of bits [21:10] within group G
  for (int i = tid; i < NPI; i += 1024) {
    unsigned k = kb[i];
    if ((k >> 22) == G) atomicAdd(&sh_sub[(k >> 10) & 4095u], 1u);
  }
  __syncthreads();
  if (tid < 64) {
    unsigned s = 0;
    for (int k = 0; k < 64; ++k) s += sh_sub[tid * 64 + k];
    sh_c64[tid] = s;
  }
  __syncthreads();
  if (tid == 0) {
    unsigned c = sh_Chi10; int C2 = 0;
    for (int g = 63; g >= 0; --g) {
      unsigned v = sh_c64[g];
      if (c + v >= KTOP) { C2 = g; break; }
      c += v;
    }
    int T12 = C2 * 64;
    for (int t2 = C2 * 64 + 63; t2 >= C2 * 64; --t2) {
      unsigned v = sh_sub[t2];
      if (c + v >= KTOP) { T12 = t2; break; }
      c += v;
    }
    sh_T = (G << 12) | (unsigned)T12;   // 22-bit threshold
    sh_Chi = c;
  }
  __syncthreads();
  const unsigned T = sh_T, Chi = sh_Chi;
  const unsigned Bcap = CAP - Chi;

  // ---- Phase B: deterministic (index-ordered) compaction
  for (int chunk = 0; chunk < 9; ++chunk) {
    int a0 = chunk * 4096 + tid * 4;
    unsigned kk[4]; bool iA[4], iB[4];
    bool act = (a0 < NPI);
    if (act) {
      uint4 kv = *(const uint4*)(kb + a0);
      kk[0] = kv.x; kk[1] = kv.y; kk[2] = kv.z; kk[3] = kv.w;
    } else { kk[0] = kk[1] = kk[2] = kk[3] = 0u; }
    #pragma unroll
    for (int e = 0; e < 4; ++e) {
      unsigned bin = kk[e] >> 10;
      iA[e] = act && (bin > T);
      iB[e] = act && (bin == T);
    }
    unsigned long long balA[4], balB[4];
    #pragma unroll
    for (int e = 0; e < 4; ++e) { balA[e] = __ballot(iA[e]); balB[e] = __ballot(iB[e]); }
    if (lane == 0) {
      unsigned sA = 0, sB = 0;
      #pragma unroll
      for (int e = 0; e < 4; ++e) { sA += (unsigned)__popcll(balA[e]); sB += (unsigned)__popcll(balB[e]); }
      sh_wcA[wave] = sA; sh_wcB[wave] = sB;
    }
    __syncthreads();
    unsigned pA = sh_nA, pB = sh_nB;
    for (int w2 = 0; w2 < wave; ++w2) { pA += sh_wcA[w2]; pB += sh_wcB[w2]; }
    unsigned long long lt = (1ULL << lane) - 1ULL;
    #pragma unroll
    for (int e = 0; e < 4; ++e) {
      pA += (unsigned)__popcll(balA[e] & lt);
      pB += (unsigned)__popcll(balB[e] & lt);
    }
    #pragma unroll
    for (int e = 0; e < 4; ++e) {
      unsigned long long packed =
          ((unsigned long long)kk[e] << 32) |
          (unsigned long long)(0xFFFFFFFFu - (unsigned)(a0 + e));
      if (iA[e]) { sh_cand[pA] = packed; ++pA; }
      if (iB[e]) { if (pB < Bcap) sh_cand[CAP - 1 - pB] = packed; ++pB; }
    }
    __syncthreads();
    if (tid == 0) {
      unsigned sA = 0, sB = 0;
      for (int w2 = 0; w2 < 16; ++w2) { sA += sh_wcA[w2]; sB += sh_wcB[w2]; }
      sh_nA += sA; sh_nB += sB;
    }
    __syncthreads();
  }
  {
    const unsigned nA  = sh_nA;
    const unsigned nBk = (sh_nB < Bcap) ? sh_nB : Bcap;
    for (int s = (int)nA + tid; s < (int)(CAP - nBk); s += 1024) sh_cand[s] = 0ULL;
  }
  __syncthreads();

  // ---- Phase C: bitonic sort 1024 u64 descending ((score desc, index asc))
  for (unsigned kk2 = 2; kk2 <= CAP; kk2 <<= 1) {
    for (unsigned jj = kk2 >> 1; jj > 0; jj >>= 1) {
      unsigned i = (unsigned)tid, p = i ^ jj;
      if (p > i) {
        unsigned long long x = sh_cand[i], y = sh_cand[p];
        bool desc = ((i & kk2) == 0);
        if ((x < y) == desc) { sh_cand[i] = y; sh_cand[p] = x; }
      }
      __syncthreads();
    }
  }

  // ---- Phase D: gather top-500 from L2-resident det planes; max_c; offsets; inval
  bool validk = false;
  float contrib = -INFINITY;
  if (tid < KTOP) {
    unsigned long long v = sh_cand[tid];
    unsigned keyk = (unsigned)(v >> 32);
    int a = (int)(0xFFFFFFFFu - (unsigned)(v & 0xFFFFFFFFull));
    if (a < 0) a = 0;                 // zero-padded slot (invalid anyway)
    const size_t P  = (size_t)NIMG * NPI;
    const size_t pa = (size_t)b * NPI + (size_t)a;
    float det[7];
    #pragma unroll
    for (int c = 0; c < 7; ++c) det[c] = dets[(size_t)c * P + pa];
    #pragma unroll
    for (int c = 0; c < 7; ++c) sh_det[tid][c] = det[c];
    validk = (keyk >= KEY001);
    float m4 = fmaxf(fmaxf(det[0], det[1]), fmaxf(det[2], det[3]));
    contrib = validk ? m4 : 0.0f;     // jnp.where(valid, boxes, 0) then global max
  }
  float r = contrib;
  #pragma unroll
  for (int off = 32; off > 0; off >>= 1) r = fmaxf(r, __shfl_xor(r, off));
  if (lane == 0) sh_red[wave] = r;
  unsigned long long bv = __ballot((tid < KTOP) && !validk);
  if (wave < 8 && lane == 0) {
    sh_inval[wave * 2]     = (unsigned)(bv & 0xFFFFFFFFull);
    sh_inval[wave * 2 + 1] = (unsigned)(bv >> 32);
  }
  __syncthreads();
  if (tid == 0) {
    float m = -INFINITY;
    for (int w2 = 0; w2 < 16; ++w2) m = fmaxf(m, sh_red[w2]);
    sh_maxc = m + 1.0f;
  }
  __syncthreads();
  const float maxc = sh_maxc;
  if (tid < KTOP) {
    float offb = sh_det[tid][6] * maxc;   // label * max_c
    #pragma unroll
    for (int d = 0; d < 4; ++d) sh_box[tid][d] = sh_det[tid][d] + offb;
  }
  __syncthreads();

  // ---- Phase E: IoU suppression bitmask (upper triangle), fully parallel
  for (int task = tid; task < KTOP * 16; task += 1024) {
    int i = task % KTOP;
    int w = task / KTOP;
    int jbase = w * 32;
    unsigned bits = 0u;
    if (jbase + 31 > i) {
      float ix1 = sh_box[i][0], iy1 = sh_box[i][1], ix2 = sh_box[i][2], iy2 = sh_box[i][3];
      float a1 = fmaxf(ix2 - ix1, 0.0f) * fmaxf(iy2 - iy1, 0.0f);
      #pragma unroll 4
      for (int jj = 0; jj < 32; ++jj) {
        int j = jbase + jj;
        if (j < KTOP && j > i) {
          float jx1 = sh_box[j][0], jy1 = sh_box[j][1];
          float jx2 = sh_box[j][2], jy2 = sh_box[j][3];
          float iw = fminf(ix2, jx2) - fmaxf(ix1, jx1);
          float ih = fminf(iy2, jy2) - fmaxf(iy1, jy1);
          float inter = fmaxf(iw, 0.0f) * fmaxf(ih, 0.0f);
          float a2 = fmaxf(jx2 - jx1, 0.0f) * fmaxf(jy2 - jy1, 0.0f);
          // iou > 0.65  <=>  inter > 0.65*(a1+a2-inter+1e-9)
          if (inter > 0.65f * (a1 + a2 - inter + 1e-9f)) bits |= (1u << jj);
        }
      }
    }
    sh_mask[i * 16 + w] = bits;
  }
  __syncthreads();

  // ---- Phase F: greedy sequential scan (wave 0); lane l<16 owns suppressed word l
  if (tid < 64) {
    unsigned sup   = (lane < 16) ? sh_inval[lane] : 0u;
    unsigned keepw = 0u;
    unsigned cur = (unsigned)__builtin_amdgcn_readlane((int)sup, 0);
    unsigned mA = (lane < 16) ? sh_mask[0 * 16 + lane] : 0u;
    unsigned mB = (lane < 16) ? sh_mask[1 * 16 + lane] : 0u;
    for (int i = 0; i < KTOP; i += 2) {
      bool ok = ((cur >> (i & 31)) & 1u) == 0u;
      if (ok) {
        sup |= mA;
        if (lane == (i >> 5)) keepw |= (1u << (i & 31));
      }
      cur = (unsigned)__builtin_amdgcn_readlane((int)sup, (i + 1) >> 5);
      mA = (lane < 16 && (i + 2) < KTOP) ? sh_mask[(i + 2) * 16 + lane] : 0u;
      bool ok2 = ((cur >> ((i + 1) & 31)) & 1u) == 0u;
      if (ok2) {
        sup |= mB;
        if (lane == ((i + 1) >> 5)) keepw |= (1u << ((i + 1) & 31));
      }
      cur = (unsigned)__builtin_amdgcn_readlane((int)sup, (i + 2) >> 5);
      mB = (lane < 16 && (i + 3) < KTOP) ? sh_mask[(i + 3) * 16 + lane] : 0u;
    }
    if (lane < 16) sh_keep[lane] = keepw;
  }
  __syncthreads();

  // ---- Phase G: write det * keep
  for (int x = tid; x < KTOP * 7; x += 1024) {
    int k = x / 7, c = x - k * 7;
    float keepf = ((sh_keep[k >> 5] >> (k & 31)) & 1u) ? 1.0f : 0.0f;
    out[(size_t)b * (KTOP * 7) + x] = sh_det[k][c] * keepf;
  }
}

extern "C" void kernel_launch(void* const* d_in, const int* in_sizes, int n_in,
                              void* d_out, int out_size, void* d_ws, size_t ws_size,
                              hipStream_t stream) {
  const float* p8  = (const float*)d_in[0];
  const float* p16 = (const float*)d_in[1];
  const float* p32 = (const float*)d_in[2];
  float* out = (float*)d_out;
  // workspace layout (~8.6 MB)
  unsigned* hist2 = (unsigned*)d_ws;                         // [8][1024]
  unsigned* keys  = hist2 + (size_t)NIMG * NGRP;             // [8][NPI]
  float*    dets  = (float*)(keys + (size_t)NIMG * NPI);     // [7][8][NPI]

  hipMemsetAsync(hist2, 0, (size_t)NIMG * NGRP * 4, stream);
  k_decode<<<dim3(33, NIMG), 256, 0, stream>>>(p8, p16, p32, keys, dets, hist2);
  k_post<<<dim3(NIMG), 1024, 0, stream>>>(hist2, keys, dets, out);
}